// Round 1
// baseline (1762.093 us; speedup 1.0000x reference)
//
#include <hip/hip_runtime.h>
#include <math.h>

// Problem constants
#define NWIN 512     // 8x8x8 windows
#define NHD  3       // heads
#define NTOK 343     // 7x7x7 tokens per window
#define HD   32      // head dim
#define CH   96      // channels
#define DIM  56      // spatial dim

__device__ __forceinline__ float grp32_sum(float v) {
    v += __shfl_xor(v, 16, 32);
    v += __shfl_xor(v, 8, 32);
    v += __shfl_xor(v, 4, 32);
    v += __shfl_xor(v, 2, 32);
    v += __shfl_xor(v, 1, 32);
    return v;  // all 32 lanes hold the sum
}

// One block per (head, window): computes q,k,v for its head, linear attention,
// depthwise 5x5x5 conv on v, writes att+fm+dwc_b into d_out (token-major,
// merged heads + window-reversed). grid = 3*512, h-major so co-resident
// blocks share weight columns in L1.
__global__ __launch_bounds__(256, 2) void attn_kernel(
    const float* __restrict__ x, const float* __restrict__ w_qkv,
    const float* __restrict__ scale_param, const float* __restrict__ pos_enc,
    const float* __restrict__ dwc_w, const float* __restrict__ dwc_b,
    float* __restrict__ y)
{
    __shared__ float v_lds[NTOK * HD];   // 43904 B : full v tile (conv + kv)
    __shared__ float kv_lds[HD * HD];    // 4096 B  : kv matrix
    __shared__ float kq_stage[8 * HD];   // 1024 B  : per-chunk k or q rows
    __shared__ float red[256];           // 1024 B  : ksum partials
    __shared__ float ksum_s[HD];
    __shared__ float sps[HD];            // softplus(scale_param)
    __shared__ float dwc_s[HD * 125];    // 16000 B : depthwise weights
    __shared__ float xstage[8 * CH];     // 3072 B  : staged x rows

    const int tid = threadIdx.x;
    const int bid = blockIdx.x;
    const int h   = bid >> 9;        // head (0..2)
    const int win = bid & 511;
    const int wd  = win >> 6;
    const int wh  = (win >> 3) & 7;
    const int ww  = win & 7;

    const int g = tid >> 5;          // token group 0..7
    const int c = tid & 31;          // channel lane

    // preload depthwise weights + softplus(scale)
    for (int i = tid; i < HD * 125; i += 256) dwc_s[i] = dwc_w[i];
    if (tid < HD) {
        float sv = scale_param[tid];
        sps[tid] = (sv > 20.f) ? sv : log1pf(expf(sv));
    }
    __syncthreads();

    const float spc = sps[c];
    const float* wk = w_qkv + (CH     + h * HD + c);
    const float* wv = w_qkv + (2 * CH + h * HD + c);
    const float* wq = w_qkv + (h * HD + c);

    const int cb = tid >> 3;          // owned kv row 0..31
    const int d0 = (tid & 7) * 4;     // owned kv col group
    float kv0 = 0.f, kv1 = 0.f, kv2 = 0.f, kv3 = 0.f;
    float ksum_reg = 0.f;

    // ---------------- Phase 1: k, v -> ksum, kv, v_lds ----------------
    for (int jc = 0; jc < NTOK; jc += 8) {
        const int nj = min(8, NTOK - jc);
        // stage x rows for this chunk (coalesced)
        for (int i = tid; i < nj * CH; i += 256) {
            int r = i / CH; int cc = i - r * CH;
            int j2 = jc + r;
            int dz = j2 / 49; int rem = j2 - dz * 49;
            int dy = rem / 7; int dxx = rem - dy * 7;
            int tok = ((wd * 7 + dz) * DIM + (wh * 7 + dy)) * DIM + (ww * 7 + dxx);
            xstage[i] = x[tok * CH + cc];
        }
        __syncthreads();

        const int j = jc + g;
        if (j < NTOK) {
            float kacc = 0.f, vacc = 0.f;
            const float* xr = &xstage[g * CH];
            #pragma unroll 8
            for (int cc = 0; cc < CH; ++cc) {
                float xv = xr[cc];
                kacc = fmaf(xv, wk[cc * 288], kacc);
                vacc = fmaf(xv, wv[cc * 288], vacc);
            }
            kacc += pos_enc[j * HD + c];
            float kp = (fmaxf(kacc, 0.f) + 1e-6f) / spc;
            float n2 = grp32_sum(kp * kp);
            float k3 = kp * kp * kp;
            float n6 = grp32_sum(k3 * k3);
            float kfin = k3 * (sqrtf(n2) / sqrtf(n6));
            v_lds[j * HD + c]    = vacc;
            kq_stage[g * HD + c] = kfin;
            ksum_reg += kfin;
        }
        __syncthreads();

        // accumulate kv[cb][d0..d0+3] over this chunk's tokens
        for (int jj = 0; jj < nj; ++jj) {
            float kk = kq_stage[jj * HD + cb];
            const float* vr = &v_lds[(jc + jj) * HD + d0];
            kv0 = fmaf(kk, vr[0], kv0);
            kv1 = fmaf(kk, vr[1], kv1);
            kv2 = fmaf(kk, vr[2], kv2);
            kv3 = fmaf(kk, vr[3], kv3);
        }
        // next iteration's post-stage barrier protects kq_stage reuse
    }

    red[tid] = ksum_reg;
    kv_lds[cb * HD + d0 + 0] = kv0;
    kv_lds[cb * HD + d0 + 1] = kv1;
    kv_lds[cb * HD + d0 + 2] = kv2;
    kv_lds[cb * HD + d0 + 3] = kv3;
    __syncthreads();
    if (tid < HD) {
        float s = 0.f;
        #pragma unroll
        for (int gg = 0; gg < 8; ++gg) s += red[gg * HD + tid];
        ksum_s[tid] = s;
    }
    __syncthreads();

    const float bias_c = dwc_b[c];
    const float ks_c   = ksum_s[c];

    // ---------------- Phase 2: q -> att, + conv(v), write y ----------------
    for (int jc = 0; jc < NTOK; jc += 8) {
        const int nj = min(8, NTOK - jc);
        for (int i = tid; i < nj * CH; i += 256) {
            int r = i / CH; int cc = i - r * CH;
            int j2 = jc + r;
            int dz = j2 / 49; int rem = j2 - dz * 49;
            int dy = rem / 7; int dxx = rem - dy * 7;
            int tok = ((wd * 7 + dz) * DIM + (wh * 7 + dy)) * DIM + (ww * 7 + dxx);
            xstage[i] = x[tok * CH + cc];
        }
        __syncthreads();

        const int j = jc + g;
        if (j < NTOK) {
            float qacc = 0.f;
            const float* xr = &xstage[g * CH];
            #pragma unroll 8
            for (int cc = 0; cc < CH; ++cc)
                qacc = fmaf(xr[cc], wq[cc * 288], qacc);

            float qp = (fmaxf(qacc, 0.f) + 1e-6f) / spc;
            float n2 = grp32_sum(qp * qp);
            float q3 = qp * qp * qp;
            float n6 = grp32_sum(q3 * q3);
            float qfin = q3 * (sqrtf(n2) / sqrtf(n6));

            float dotv = grp32_sum(qfin * ks_c);
            float z = 1.f / (dotv + 1e-6f);

            kq_stage[g * HD + c] = qfin;   // same-wave write->read, in-order LDS
            float att = 0.f;
            #pragma unroll 8
            for (int c2 = 0; c2 < HD; ++c2)
                att = fmaf(kq_stage[g * HD + c2], kv_lds[c2 * HD + c], att);
            att *= z;

            // depthwise 5x5x5 conv on v (cross-correlation, pad 2)
            int dz = j / 49; int rem = j - dz * 49;
            int dy = rem / 7; int dxx = rem - dy * 7;
            float fm = 0.f;
            #pragma unroll
            for (int ka = 0; ka < 5; ++ka) {
                int za = dz + ka - 2;
                if ((unsigned)za >= 7u) continue;
                #pragma unroll
                for (int kb = 0; kb < 5; ++kb) {
                    int zb = dy + kb - 2;
                    if ((unsigned)zb >= 7u) continue;
                    const float* vb = &v_lds[(za * 49 + zb * 7) * HD + c];
                    const float* wb = &dwc_s[c * 125 + ka * 25 + kb * 5];
                    int kc0 = max(0, 2 - dxx), kc1 = min(5, 9 - dxx);
                    for (int kc = kc0; kc < kc1; ++kc)
                        fm = fmaf(vb[(dxx + kc - 2) * HD], wb[kc], fm);
                }
            }

            int tok = ((wd * 7 + dz) * DIM + (wh * 7 + dy)) * DIM + (ww * 7 + dxx);
            y[tok * CH + h * HD + c] = att + fm + bias_c;
        }
        __syncthreads();   // protect xstage before next chunk's staging
    }
}

// In-place projection: d_out <- d_out @ w_proj + b_proj.
// 256 tokens/block staged in padded LDS; each thread: 4 tokens x 24 outputs.
__global__ __launch_bounds__(256, 1) void proj_kernel(
    const float* __restrict__ wp, const float* __restrict__ bp,
    float* __restrict__ y)
{
    __shared__ float yt[256 * 97];   // 99328 B, pad->conflict-free
    __shared__ float wl[96 * 96];    // 36864 B

    const int tid = threadIdx.x;
    const int base = blockIdx.x * 256;

    for (int i = tid; i < 96 * 96; i += 256) wl[i] = wp[i];
    for (int i = tid; i < 256 * 96; i += 256) {
        int r = i / 96; int ch2 = i - r * 96;
        yt[r * 97 + ch2] = y[(base + r) * 96 + ch2];
    }
    __syncthreads();

    const int tokg = tid & 63;       // token subgroup (tokens tokg + 64*i)
    const int outg = tid >> 6;       // output group (outputs outg*24 + jj)

    float acc[4][24];
    #pragma unroll
    for (int jj = 0; jj < 24; ++jj) {
        float b = bp[outg * 24 + jj];
        acc[0][jj] = b; acc[1][jj] = b; acc[2][jj] = b; acc[3][jj] = b;
    }

    for (int cc = 0; cc < 96; ++cc) {
        float y0 = yt[(tokg)       * 97 + cc];
        float y1 = yt[(tokg + 64)  * 97 + cc];
        float y2 = yt[(tokg + 128) * 97 + cc];
        float y3 = yt[(tokg + 192) * 97 + cc];
        const float* wrow = &wl[cc * 96 + outg * 24];
        #pragma unroll
        for (int jj = 0; jj < 24; ++jj) {
            float wvv = wrow[jj];
            acc[0][jj] = fmaf(y0, wvv, acc[0][jj]);
            acc[1][jj] = fmaf(y1, wvv, acc[1][jj]);
            acc[2][jj] = fmaf(y2, wvv, acc[2][jj]);
            acc[3][jj] = fmaf(y3, wvv, acc[3][jj]);
        }
    }
    __syncthreads();   // all reads done before in-place writes (same block only)

    #pragma unroll
    for (int i = 0; i < 4; ++i) {
        int tok = base + tokg + 64 * i;
        #pragma unroll
        for (int jj = 0; jj < 24; ++jj)
            y[tok * 96 + outg * 24 + jj] = acc[i][jj];
    }
}

extern "C" void kernel_launch(void* const* d_in, const int* in_sizes, int n_in,
                              void* d_out, int out_size, void* d_ws, size_t ws_size,
                              hipStream_t stream) {
    const float* x           = (const float*)d_in[0];
    const float* w_qkv       = (const float*)d_in[1];
    const float* scale_param = (const float*)d_in[2];
    const float* pos_enc     = (const float*)d_in[3];
    const float* dwc_w       = (const float*)d_in[4];
    const float* dwc_b       = (const float*)d_in[5];
    const float* w_proj      = (const float*)d_in[6];
    const float* b_proj      = (const float*)d_in[7];
    float* out = (float*)d_out;

    attn_kernel<<<dim3(NHD * NWIN), dim3(256), 0, stream>>>(
        x, w_qkv, scale_param, pos_enc, dwc_w, dwc_b, out);
    proj_kernel<<<dim3(686), dim3(256), 0, stream>>>(w_proj, b_proj, out);
}

// Round 2
// 700.235 us; speedup vs baseline: 2.5164x; 2.5164x over previous
//
#include <hip/hip_runtime.h>
#include <math.h>

// Problem constants
#define NWIN 512     // 8x8x8 windows
#define NHD  3       // heads
#define NTOK 343     // 7x7x7 tokens per window
#define HD   32      // head dim
#define CH   96      // channels
#define DIM  56      // spatial dim
#define CHUNK 32     // tokens per staged chunk

__device__ __forceinline__ float grp32_sum(float v) {
    v += __shfl_xor(v, 16, 32);
    v += __shfl_xor(v, 8, 32);
    v += __shfl_xor(v, 4, 32);
    v += __shfl_xor(v, 2, 32);
    v += __shfl_xor(v, 1, 32);
    return v;  // all 32 lanes hold the sum
}

// One block per (head, window). Phase A: k,v GEMM (4-token register blocking)
// -> kv, ksum, v_lds. Phase B1: q GEMM -> att, write y. Phase B2: depthwise
// conv on v_lds, y += fm + bias. LDS ~65.7KB -> 2 blocks/CU.
__global__ __launch_bounds__(256, 2) void attn_kernel(
    const float* __restrict__ x, const float* __restrict__ w_qkv,
    const float* __restrict__ scale_param, const float* __restrict__ pos_enc,
    const float* __restrict__ dwc_w, const float* __restrict__ dwc_b,
    float* __restrict__ y)
{
    __shared__ float v_lds[NTOK * HD];                    // 43904 B
    __shared__ union U {
        struct S { float x[CHUNK * CH]; float kq[CHUNK * HD]; } s;  // 16384 B
        float dwc[HD * 125];                              // 16000 B (aliased)
    } u;
    __shared__ float kv_lds[HD * HD];                     // 4096 B
    __shared__ float red[256];
    __shared__ float ksum_s[HD];
    __shared__ float sps[HD];

    const int tid = threadIdx.x;
    const int bid = blockIdx.x;
    const int h   = bid >> 9;        // head 0..2
    const int win = bid & 511;
    const int wd  = win >> 6, wh = (win >> 3) & 7, ww = win & 7;
    const int g8  = tid >> 5;        // token group 0..7 (4 tokens each)
    const int c   = tid & 31;        // channel lane

    if (tid < HD) {
        float sv = scale_param[tid];
        sps[tid] = (sv > 20.f) ? sv : log1pf(expf(sv));
    }
    __syncthreads();
    const float spc = sps[c];

    const float* wq = w_qkv + (h * HD + c);
    const float* wk = wq + CH;
    const float* wv = wq + 2 * CH;

    const int cb = tid >> 3;          // owned kv row 0..31
    const int d0 = (tid & 7) * 4;     // owned kv col group
    float kva[4] = {0.f, 0.f, 0.f, 0.f};
    float ksum_reg = 0.f;

    // ---------------- Phase A: k,v -> ksum, kv, v_lds ----------------
    for (int jc = 0; jc < NTOK; jc += CHUNK) {
        const int nj = min(CHUNK, NTOK - jc);
        // stage x chunk (float4, coalesced)
        const int nf4 = nj * (CH / 4);
        for (int i = tid; i < nf4; i += 256) {
            int r = i / 24, c4 = i - r * 24;
            int j2 = jc + r;
            int dz = j2 / 49, rem = j2 - dz * 49;
            int dy = rem / 7, dx = rem - dy * 7;
            int tok = ((wd * 7 + dz) * DIM + (wh * 7 + dy)) * DIM + (ww * 7 + dx);
            ((float4*)u.s.x)[i] = ((const float4*)(x + (size_t)tok * CH))[c4];
        }
        __syncthreads();

        float ka[4] = {0.f, 0.f, 0.f, 0.f}, va[4] = {0.f, 0.f, 0.f, 0.f};
        const float* xr = &u.s.x[g8 * 4 * CH];
        #pragma unroll 8
        for (int cc = 0; cc < CH; ++cc) {
            float wkv = wk[cc * 288];
            float wvv = wv[cc * 288];
            float x0 = xr[cc], x1 = xr[CH + cc], x2 = xr[2 * CH + cc], x3 = xr[3 * CH + cc];
            ka[0] = fmaf(x0, wkv, ka[0]); va[0] = fmaf(x0, wvv, va[0]);
            ka[1] = fmaf(x1, wkv, ka[1]); va[1] = fmaf(x1, wvv, va[1]);
            ka[2] = fmaf(x2, wkv, ka[2]); va[2] = fmaf(x2, wvv, va[2]);
            ka[3] = fmaf(x3, wkv, ka[3]); va[3] = fmaf(x3, wvv, va[3]);
        }
        #pragma unroll
        for (int i2 = 0; i2 < 4; ++i2) {
            int t = g8 * 4 + i2;
            int j = jc + t;
            bool valid = (t < nj);             // group-uniform
            int jj = valid ? j : 0;
            float kacc = ka[i2] + pos_enc[jj * HD + c];
            float kp = (fmaxf(kacc, 0.f) + 1e-6f) / spc;
            float n2 = grp32_sum(kp * kp);
            float k3 = kp * kp * kp;
            float n6 = grp32_sum(k3 * k3);
            float kfin = k3 * sqrtf(n2 / n6);
            if (valid) {
                v_lds[j * HD + c]  = va[i2];
                u.s.kq[t * HD + c] = kfin;
                ksum_reg += kfin;
            }
        }
        __syncthreads();

        // kv accumulation (kv row cb, cols d0..d0+3) over this chunk
        for (int j = 0; j < nj; ++j) {
            float kk = u.s.kq[j * HD + cb];
            float4 vr = *(const float4*)&v_lds[(jc + j) * HD + d0];
            kva[0] = fmaf(kk, vr.x, kva[0]);
            kva[1] = fmaf(kk, vr.y, kva[1]);
            kva[2] = fmaf(kk, vr.z, kva[2]);
            kva[3] = fmaf(kk, vr.w, kva[3]);
        }
        // no barrier needed: next chunk's kq writes are after its stage barrier
    }

    red[tid] = ksum_reg;
    kv_lds[cb * HD + d0 + 0] = kva[0];
    kv_lds[cb * HD + d0 + 1] = kva[1];
    kv_lds[cb * HD + d0 + 2] = kva[2];
    kv_lds[cb * HD + d0 + 3] = kva[3];
    __syncthreads();
    if (tid < HD) {
        float s2 = 0.f;
        #pragma unroll
        for (int gg = 0; gg < 8; ++gg) s2 += red[gg * HD + tid];
        ksum_s[tid] = s2;
    }
    __syncthreads();

    // ---------------- Phase B1: q -> att, write y ----------------
    const float ks_c = ksum_s[c];
    float kvc[HD];                      // kv column c in registers
    #pragma unroll
    for (int c2 = 0; c2 < HD; ++c2) kvc[c2] = kv_lds[c2 * HD + c];

    for (int jc = 0; jc < NTOK; jc += CHUNK) {
        const int nj = min(CHUNK, NTOK - jc);
        const int nf4 = nj * (CH / 4);
        for (int i = tid; i < nf4; i += 256) {
            int r = i / 24, c4 = i - r * 24;
            int j2 = jc + r;
            int dz = j2 / 49, rem = j2 - dz * 49;
            int dy = rem / 7, dx = rem - dy * 7;
            int tok = ((wd * 7 + dz) * DIM + (wh * 7 + dy)) * DIM + (ww * 7 + dx);
            ((float4*)u.s.x)[i] = ((const float4*)(x + (size_t)tok * CH))[c4];
        }
        __syncthreads();

        float qa[4] = {0.f, 0.f, 0.f, 0.f};
        const float* xr = &u.s.x[g8 * 4 * CH];
        #pragma unroll 8
        for (int cc = 0; cc < CH; ++cc) {
            float wqv = wq[cc * 288];
            qa[0] = fmaf(xr[cc],          wqv, qa[0]);
            qa[1] = fmaf(xr[CH + cc],     wqv, qa[1]);
            qa[2] = fmaf(xr[2 * CH + cc], wqv, qa[2]);
            qa[3] = fmaf(xr[3 * CH + cc], wqv, qa[3]);
        }
        float zreg[4];
        #pragma unroll
        for (int i2 = 0; i2 < 4; ++i2) {
            int t = g8 * 4 + i2;
            bool valid = (t < nj);
            float qp = (fmaxf(qa[i2], 0.f) + 1e-6f) / spc;
            float n2 = grp32_sum(qp * qp);
            float q3 = qp * qp * qp;
            float n6 = grp32_sum(q3 * q3);
            float qfin = q3 * sqrtf(n2 / n6);
            zreg[i2] = 1.f / (grp32_sum(qfin * ks_c) + 1e-6f);
            if (valid) u.s.kq[t * HD + c] = qfin;
        }
        __syncthreads();

        #pragma unroll
        for (int i2 = 0; i2 < 4; ++i2) {
            int t = g8 * 4 + i2;
            int j = jc + t;
            if (t < nj) {
                float att = 0.f;
                #pragma unroll
                for (int c2 = 0; c2 < HD; c2 += 4) {
                    float4 qv = *(const float4*)&u.s.kq[t * HD + c2];
                    att = fmaf(qv.x, kvc[c2],     att);
                    att = fmaf(qv.y, kvc[c2 + 1], att);
                    att = fmaf(qv.z, kvc[c2 + 2], att);
                    att = fmaf(qv.w, kvc[c2 + 3], att);
                }
                int dz = j / 49, rem = j - dz * 49;
                int dy = rem / 7, dx = rem - dy * 7;
                int tok = ((wd * 7 + dz) * DIM + (wh * 7 + dy)) * DIM + (ww * 7 + dx);
                y[(size_t)tok * CH + h * HD + c] = att * zreg[i2];
            }
        }
        // no barrier needed: next chunk's kq writes are after its stage barrier
    }

    __threadfence_block();   // make B1's y writes visible to B2's RMW reads
    __syncthreads();

    // ---------------- Phase B2: depthwise 5x5x5 conv, y += fm + bias ----
    for (int i = tid; i < HD * 125; i += 256) u.dwc[i] = dwc_w[i];
    __syncthreads();

    const float bias_c = dwc_b[c];
    for (int it = g8; it < 49; it += 8) {
        int dz = it / 7, dy = it - dz * 7;
        float fm[7] = {0.f, 0.f, 0.f, 0.f, 0.f, 0.f, 0.f};
        #pragma unroll
        for (int ka2 = 0; ka2 < 5; ++ka2) {
            int za = dz + ka2 - 2;
            if ((unsigned)za >= 7u) continue;
            #pragma unroll
            for (int kb = 0; kb < 5; ++kb) {
                int zb = dy + kb - 2;
                if ((unsigned)zb >= 7u) continue;
                const float* vb = &v_lds[(za * 49 + zb * 7) * HD + c];
                float vr[7];
                #pragma unroll
                for (int xx = 0; xx < 7; ++xx) vr[xx] = vb[xx * HD];
                const float* wb = &u.dwc[c * 125 + ka2 * 25 + kb * 5];
                float w0 = wb[0], w1 = wb[1], w2 = wb[2], w3 = wb[3], w4 = wb[4];
                #pragma unroll
                for (int dx2 = 0; dx2 < 7; ++dx2) {
                    if (dx2 - 2 >= 0) fm[dx2] = fmaf(vr[dx2 - 2], w0, fm[dx2]);
                    if (dx2 - 1 >= 0) fm[dx2] = fmaf(vr[dx2 - 1], w1, fm[dx2]);
                    fm[dx2] = fmaf(vr[dx2], w2, fm[dx2]);
                    if (dx2 + 1 <= 6) fm[dx2] = fmaf(vr[dx2 + 1], w3, fm[dx2]);
                    if (dx2 + 2 <= 6) fm[dx2] = fmaf(vr[dx2 + 2], w4, fm[dx2]);
                }
            }
        }
        int tokbase = ((wd * 7 + dz) * DIM + (wh * 7 + dy)) * DIM + ww * 7;
        #pragma unroll
        for (int dx2 = 0; dx2 < 7; ++dx2) {
            float* yp = &y[(size_t)(tokbase + dx2) * CH + h * HD + c];
            *yp += fm[dx2] + bias_c;
        }
    }
}

// In-place projection: d_out <- d_out @ w_proj + b_proj.
__global__ __launch_bounds__(256, 1) void proj_kernel(
    const float* __restrict__ wp, const float* __restrict__ bp,
    float* __restrict__ y)
{
    __shared__ float yt[256 * 97];   // 99328 B, pad->conflict-free
    __shared__ float wl[96 * 96];    // 36864 B

    const int tid = threadIdx.x;
    const int base = blockIdx.x * 256;

    for (int i = tid; i < 96 * 96; i += 256) wl[i] = wp[i];
    for (int i = tid; i < 256 * 96; i += 256) {
        int r = i / 96; int ch2 = i - r * 96;
        yt[r * 97 + ch2] = y[(base + r) * 96 + ch2];
    }
    __syncthreads();

    const int tokg = tid & 63;
    const int outg = tid >> 6;

    float acc[4][24];
    #pragma unroll
    for (int jj = 0; jj < 24; ++jj) {
        float b = bp[outg * 24 + jj];
        acc[0][jj] = b; acc[1][jj] = b; acc[2][jj] = b; acc[3][jj] = b;
    }

    for (int cc = 0; cc < 96; ++cc) {
        float y0 = yt[(tokg)       * 97 + cc];
        float y1 = yt[(tokg + 64)  * 97 + cc];
        float y2 = yt[(tokg + 128) * 97 + cc];
        float y3 = yt[(tokg + 192) * 97 + cc];
        const float* wrow = &wl[cc * 96 + outg * 24];
        #pragma unroll
        for (int jj = 0; jj < 24; ++jj) {
            float wvv = wrow[jj];
            acc[0][jj] = fmaf(y0, wvv, acc[0][jj]);
            acc[1][jj] = fmaf(y1, wvv, acc[1][jj]);
            acc[2][jj] = fmaf(y2, wvv, acc[2][jj]);
            acc[3][jj] = fmaf(y3, wvv, acc[3][jj]);
        }
    }
    __syncthreads();

    #pragma unroll
    for (int i = 0; i < 4; ++i) {
        int tok = base + tokg + 64 * i;
        #pragma unroll
        for (int jj = 0; jj < 24; ++jj)
            y[tok * 96 + outg * 24 + jj] = acc[i][jj];
    }
}

extern "C" void kernel_launch(void* const* d_in, const int* in_sizes, int n_in,
                              void* d_out, int out_size, void* d_ws, size_t ws_size,
                              hipStream_t stream) {
    const float* x           = (const float*)d_in[0];
    const float* w_qkv       = (const float*)d_in[1];
    const float* scale_param = (const float*)d_in[2];
    const float* pos_enc     = (const float*)d_in[3];
    const float* dwc_w       = (const float*)d_in[4];
    const float* dwc_b       = (const float*)d_in[5];
    const float* w_proj      = (const float*)d_in[6];
    const float* b_proj      = (const float*)d_in[7];
    float* out = (float*)d_out;

    attn_kernel<<<dim3(NHD * NWIN), dim3(256), 0, stream>>>(
        x, w_qkv, scale_param, pos_enc, dwc_w, dwc_b, out);
    proj_kernel<<<dim3(686), dim3(256), 0, stream>>>(w_proj, b_proj, out);
}